// Round 9
// baseline (626.154 us; speedup 1.0000x reference)
//
#include <hip/hip_runtime.h>
#include <math.h>

#define IMGD 224
#define HW 50176      // 224*224
#define NK 100
#define NB 8
#define OUT_PER_B 76800   // 100*16*16*3 = 300*256
#define NCHUNK 131        // OpenBLAS k-blocking of 50176: 129x384, 320, 320

// ratio = 10.0 / sqrt(224*224/100) in f64, rounded to f32 when numpy multiplies
// the f32 arange arrays by the weak python scalar.
static __device__ __forceinline__ float ratio_f32() {
  return (float)(10.0 / sqrt(224.0 * 224.0 / 100.0));
}

// ---------- resize matrix A[16][224], jax linear+antialias semantics ----------
__global__ void build_A_kernel(float* __restrict__ A) {
  __shared__ float red[256];
  int p = blockIdx.x;   // 0..15
  int h = threadIdx.x;  // 0..255
  float tri = 0.0f;
  if (h < IMGD) {
    float center = (p + 0.5f) * 14.0f - 0.5f;       // sample_f
    float xd = fabsf(center - (float)h) / 14.0f;    // / kernel_scale
    tri = fmaxf(0.0f, 1.0f - xd);
  }
  red[h] = tri;
  __syncthreads();
  for (int s = 128; s > 0; s >>= 1) {
    if (h < s) red[h] += red[h + s];
    __syncthreads();
  }
  float Z = red[0];
  if (h < IMGD) A[p * IMGD + h] = tri / Z;
}

// ---------- SLIC: grid-init centers (f32, mirroring numpy) + c2 ----------
__global__ void init_centers_kernel(const float* __restrict__ x,
                                    float* __restrict__ centers,
                                    float* __restrict__ c2g) {
  int b = blockIdx.x, k = threadIdx.x;
  if (k >= NK) return;
  int gy = k / 10, gx = k % 10;
  int cy = (int)((gy + 0.5) * 224.0 / 10.0);  // trunc like .astype(int32)
  int cx = (int)((gx + 0.5) * 224.0 / 10.0);
  int i = cy * IMGD + cx;
  const float ratio = ratio_f32();
  float c0 = x[((size_t)b * 3 + 0) * HW + i];
  float c1 = x[((size_t)b * 3 + 1) * HW + i];
  float c2 = x[((size_t)b * 3 + 2) * HW + i];
  float c3 = __fmul_rn((float)cy, ratio);
  float c4 = __fmul_rn((float)cx, ratio);
  float* c = centers + ((size_t)b * NK + k) * 5;
  c[0] = c0; c[1] = c1; c[2] = c2; c[3] = c3; c[4] = c4;
  // c2 = np.sum(centers*centers, axis=1): rounded products, sequential adds
  float s = __fmul_rn(c0, c0);
  s = __fadd_rn(s, __fmul_rn(c1, c1));
  s = __fadd_rn(s, __fmul_rn(c2, c2));
  s = __fadd_rn(s, __fmul_rn(c3, c3));
  s = __fadd_rn(s, __fmul_rn(c4, c4));
  c2g[(size_t)b * NK + k] = s;
}

// distance op sequence — the single source of truth for bit-exactness:
// dot = fmul(f0,c0); fma(f1,c1); fma(f2,c2); fma(f3,c3); fma(f4,c4)
// d   = fsub(fadd(fsq, c2k), fmul(2, dot))
static __device__ __forceinline__ float dist5(float f0, float f1, float f2,
                                              float f3, float f4, float fsq,
                                              float4 c4v, float2 c2v) {
  float dot = __fmul_rn(f0, c4v.x);
  dot = __fmaf_rn(f1, c4v.y, dot);
  dot = __fmaf_rn(f2, c4v.z, dot);
  dot = __fmaf_rn(f3, c4v.w, dot);
  dot = __fmaf_rn(f4, c2v.x, dot);
  return __fsub_rn(__fadd_rn(fsq, c2v.y), __fmul_rn(2.0f, dot));
}

// fsq = np.sum(feat*feat): rounded products, sequential adds, no FMA
static __device__ __forceinline__ float fsq5(float f0, float f1, float f2,
                                             float f3, float f4) {
  float s = __fmul_rn(f0, f0);
  s = __fadd_rn(s, __fmul_rn(f1, f1));
  s = __fadd_rn(s, __fmul_rn(f2, f2));
  s = __fadd_rn(s, __fmul_rn(f3, f3));
  s = __fadd_rn(s, __fmul_rn(f4, f4));
  return s;
}

// ---------- fused assign+partial for one OpenBLAS k-block chunk ----------
// Assign in-block (identical ops to full assign). Partial sums via stable
// counting-sort VALUE compaction: scan walks consecutive LDS addresses
// (no dependent-index chain); per-(k,chunk) add order stays ascending-pixel
// -> bit-identical to the sequential reference.
__global__ void __launch_bounds__(256) fused_assign_partial_kernel(
    const float* __restrict__ x, const float* __restrict__ centers,
    const float* __restrict__ c2g, float* __restrict__ partials_t) {
  __shared__ float4 ck4[NK];
  __shared__ float2 ck2[NK];
  __shared__ unsigned int mask[NK * 12];    // 12 groups of 32 pixels
  __shared__ unsigned short ppk[NK * 12];   // per-(k,g) exclusive popcount prefix
  __shared__ float4 cval4[384];             // compacted {r,g,b,f3}, ascending t per k
  __shared__ float  cvalf[384];             // compacted f4
  __shared__ int cnt[128];
  __shared__ int offx[128];                 // inclusive prefix of cnt
  __shared__ int wtot;
  int c = blockIdx.x, b = blockIdx.y;
  int tid = threadIdx.x;
  int start = (c < 129) ? c * 384 : 49536 + (c - 129) * 320;
  int len   = (c < 129) ? 384 : 320;

  const float* cb = centers + (size_t)b * NK * 5;
  const float* c2b = c2g + (size_t)b * NK;
  if (tid < NK) {
    ck4[tid] = make_float4(cb[tid * 5 + 0], cb[tid * 5 + 1], cb[tid * 5 + 2], cb[tid * 5 + 3]);
    ck2[tid] = make_float2(cb[tid * 5 + 4], c2b[tid]);
  }
  for (int t = tid; t < NK * 12; t += 256) mask[t] = 0u;
  __syncthreads();

  const float* x0 = x + (size_t)b * 3 * HW;
  const float ratio = ratio_f32();

  bool v0 = true;                 // tid < 256 <= len always
  int t1 = 256 + tid;
  bool v1 = t1 < len;

  int i0 = start + tid;
  int y0 = i0 / IMGD, w0 = i0 - y0 * IMGD;
  float a0 = x0[i0], a1 = x0[HW + i0], a2 = x0[2 * HW + i0];
  float a3 = __fmul_rn((float)y0, ratio), a4 = __fmul_rn((float)w0, ratio);
  float aq = fsq5(a0, a1, a2, a3, a4);

  int i1 = start + (v1 ? t1 : 0);
  int y1 = i1 / IMGD, w1 = i1 - y1 * IMGD;
  float e0 = x0[i1], e1 = x0[HW + i1], e2 = x0[2 * HW + i1];
  float e3 = __fmul_rn((float)y1, ratio), e4 = __fmul_rn((float)w1, ratio);
  float eq = fsq5(e0, e1, e2, e3, e4);

  float bestA = 3.4e38f, bestE = 3.4e38f;
  int bkA = 0, bkE = 0;
  for (int k = 0; k < NK; ++k) {
    float4 c4v = ck4[k];
    float2 c2v = ck2[k];
    float dA = dist5(a0, a1, a2, a3, a4, aq, c4v, c2v);
    float dE = dist5(e0, e1, e2, e3, e4, eq, c4v, c2v);
    if (dA < bestA) { bestA = dA; bkA = k; }  // first-index wins (np.argmin)
    if (dE < bestE) { bestE = dE; bkE = k; }
  }
  atomicOr(&mask[bkA * 12 + (tid >> 5)], 1u << (tid & 31));
  if (v1) atomicOr(&mask[bkE * 12 + (t1 >> 5)], 1u << (t1 & 31));
  __syncthreads();

  // per-k cumulative popcounts over the 12 groups
  int myCnt = 0;
  if (tid < NK) {
    int s = 0;
    for (int g = 0; g < 12; ++g) {
      ppk[tid * 12 + g] = (unsigned short)s;
      s += __popc(mask[tid * 12 + g]);
    }
    myCnt = s;
  }
  if (tid < 128) cnt[tid] = myCnt;
  __syncthreads();

  // inclusive prefix over 128 counts: shfl scan per wave + cross-wave fixup
  int v = (tid < 128) ? cnt[tid] : 0;
  if (tid < 128) {
    for (int d = 1; d < 64; d <<= 1) {
      int u = __shfl_up(v, d, 64);
      if ((tid & 63) >= d) v += u;
    }
  }
  if (tid == 63) wtot = v;
  __syncthreads();
  if (tid >= 64 && tid < 128) v += wtot;
  if (tid < 128) offx[tid] = v;
  __syncthreads();

  // stable VALUE scatter: pos = (off[k]-cnt[k]) + rank_within_k(t)
  {
    int g = tid >> 5, j = tid & 31;
    int rank = ppk[bkA * 12 + g] + __popc(mask[bkA * 12 + g] & ((1u << j) - 1u));
    int pos = offx[bkA] - cnt[bkA] + rank;
    cval4[pos] = make_float4(a0, a1, a2, a3);
    cvalf[pos] = a4;
  }
  if (v1) {
    int g = t1 >> 5, j = t1 & 31;
    int rank = ppk[bkE * 12 + g] + __popc(mask[bkE * 12 + g] & ((1u << j) - 1u));
    int pos = offx[bkE] - cnt[bkE] + rank;
    cval4[pos] = make_float4(e0, e1, e2, e3);
    cvalf[pos] = e4;
  }
  __syncthreads();

  // scan: thread k walks its consecutive compacted range (ascending t)
  if (tid < NK) {
    int n = cnt[tid];
    int base = offx[tid] - n;
    float s0 = 0.f, s1 = 0.f, s2 = 0.f, s3 = 0.f, s4 = 0.f, s5 = 0.f;
    for (int m = 0; m < n; ++m) {
      float4 vv = cval4[base + m];   // consecutive addresses: pipelineable
      float ww = cvalf[base + m];
      s0 = __fadd_rn(s0, vv.x);
      s1 = __fadd_rn(s1, vv.y);
      s2 = __fadd_rn(s2, vv.z);
      s3 = __fadd_rn(s3, vv.w);
      s4 = __fadd_rn(s4, ww);
      s5 += 1.0f;  // counts: exact
    }
    // transposed layout [b][k][j][c] so combine reads contiguous
    float* p = partials_t + (((size_t)b * NK + tid) * 6) * NCHUNK + c;
    p[0 * NCHUNK] = s0; p[1 * NCHUNK] = s1; p[2 * NCHUNK] = s2;
    p[3 * NCHUNK] = s3; p[4 * NCHUNK] = s4; p[5 * NCHUNK] = s5;
  }
}

// ---------- combine k-blocks in order + centroid update + c2 (all f32) ----------
// 6 independent 131-step chains per (b,k), contiguous addresses each.
__global__ void combine_update_kernel(float* __restrict__ centers,
                                      const float* __restrict__ partials_t,
                                      float* __restrict__ c2g) {
  int b = blockIdx.x, k = threadIdx.x;
  if (k >= NK) return;
  const float* base = partials_t + (((size_t)b * NK + k) * 6) * NCHUNK;
  float s0 = base[0 * NCHUNK], s1 = base[1 * NCHUNK], s2 = base[2 * NCHUNK];
  float s3 = base[3 * NCHUNK], s4 = base[4 * NCHUNK], s5 = base[5 * NCHUNK];
  for (int c = 1; c < NCHUNK; ++c) {   // ascending chunk order: C += block_c
    s0 = __fadd_rn(s0, base[0 * NCHUNK + c]);
    s1 = __fadd_rn(s1, base[1 * NCHUNK + c]);
    s2 = __fadd_rn(s2, base[2 * NCHUNK + c]);
    s3 = __fadd_rn(s3, base[3 * NCHUNK + c]);
    s4 = __fadd_rn(s4, base[4 * NCHUNK + c]);
    s5 = __fadd_rn(s5, base[5 * NCHUNK + c]);
  }
  float* cc = centers + ((size_t)b * NK + k) * 5;
  if (s5 > 0.0f) {                  // where(cnt>0, new, centers)
    float m = fmaxf(s5, 1.0f);      // np.maximum(cnt, 1.0): exact int in f32
    cc[0] = __fdiv_rn(s0, m);
    cc[1] = __fdiv_rn(s1, m);
    cc[2] = __fdiv_rn(s2, m);
    cc[3] = __fdiv_rn(s3, m);
    cc[4] = __fdiv_rn(s4, m);
  }
  // recompute c2 from the (possibly unchanged) stored center, same op order
  float c0 = cc[0], c1 = cc[1], c2 = cc[2], c3 = cc[3], c4 = cc[4];
  float t = __fmul_rn(c0, c0);
  t = __fadd_rn(t, __fmul_rn(c1, c1));
  t = __fadd_rn(t, __fmul_rn(c2, c2));
  t = __fadd_rn(t, __fmul_rn(c3, c3));
  t = __fadd_rn(t, __fmul_rn(c4, c4));
  c2g[(size_t)b * NK + k] = t;
}

// ---------- final full-image assignment: 4 px/thread, packed LDS centers ----------
__global__ void __launch_bounds__(256) assign_kernel(
    const float* __restrict__ x, const float* __restrict__ centers,
    const float* __restrict__ c2g, int* __restrict__ labels) {
  __shared__ float4 ck4[NK];
  __shared__ float2 ck2[NK];
  int b = blockIdx.y;
  int tid = threadIdx.x;
  int base = blockIdx.x * 1024;   // grid.x = 49 -> 49*1024 = 50176 exact

  const float* cb = centers + (size_t)b * NK * 5;
  const float* c2b = c2g + (size_t)b * NK;
  for (int k = tid; k < NK; k += 256) {
    ck4[k] = make_float4(cb[k * 5 + 0], cb[k * 5 + 1], cb[k * 5 + 2], cb[k * 5 + 3]);
    ck2[k] = make_float2(cb[k * 5 + 4], c2b[k]);
  }
  __syncthreads();

  const float* x0 = x + (size_t)b * 3 * HW;
  const float ratio = ratio_f32();
  float f0[4], f1[4], f2[4], f3[4], f4[4], fq[4];
  float best[4]; int bk[4];
  for (int r = 0; r < 4; ++r) {
    int i = base + r * 256 + tid;   // coalesced
    int y = i / IMGD, xw = i - y * IMGD;
    f0[r] = x0[i]; f1[r] = x0[HW + i]; f2[r] = x0[2 * HW + i];
    f3[r] = __fmul_rn((float)y, ratio);
    f4[r] = __fmul_rn((float)xw, ratio);
    fq[r] = fsq5(f0[r], f1[r], f2[r], f3[r], f4[r]);
    best[r] = 3.4e38f; bk[r] = 0;
  }
  for (int k = 0; k < NK; ++k) {
    float4 c4v = ck4[k];
    float2 c2v = ck2[k];
    for (int r = 0; r < 4; ++r) {
      float d = dist5(f0[r], f1[r], f2[r], f3[r], f4[r], fq[r], c4v, c2v);
      if (d < best[r]) { best[r] = d; bk[r] = k; }  // first-index wins
    }
  }
  int* lb = labels + (size_t)b * HW;
  for (int r = 0; r < 4; ++r) lb[base + r * 256 + tid] = bk[r];
}

// ---------- embed: block = (b,p,q); LDS bins per (k,c); direct stores ----------
__global__ void __launch_bounds__(256) embed_kernel(
    const float* __restrict__ x, const int* __restrict__ labels,
    const float* __restrict__ A, float* __restrict__ out) {
  __shared__ float sk[NK * 3];
  int b = blockIdx.y;
  int p = blockIdx.x >> 4;
  int q = blockIdx.x & 15;
  int tid = threadIdx.x;
  for (int t = tid; t < NK * 3; t += 256) sk[t] = 0.0f;
  __syncthreads();

  // A[p,h] support: h in [14p-7, 14p+20] clipped
  int h0 = max(0, 14 * p - 7), h1 = min(IMGD - 1, 14 * p + 20);
  int w0 = max(0, 14 * q - 7), w1 = min(IMGD - 1, 14 * q + 20);
  int hl = h1 - h0 + 1, wl = w1 - w0 + 1;
  int n = hl * wl;

  const float* xb = x + (size_t)b * 3 * HW;
  const int* lb = labels + (size_t)b * HW;
  const float* Ap = A + p * IMGD;
  const float* Aq = A + q * IMGD;

  for (int idx = tid; idx < n; idx += 256) {
    int dh = idx / wl;
    int hh = h0 + dh;
    int ww = w0 + (idx - dh * wl);
    int i = hh * IMGD + ww;
    float wgt = Ap[hh] * Aq[ww];
    int k = lb[i];
    atomicAdd(&sk[k * 3 + 0], wgt * xb[i]);
    atomicAdd(&sk[k * 3 + 1], wgt * xb[HW + i]);
    atomicAdd(&sk[k * 3 + 2], wgt * xb[2 * HW + i]);
  }
  __syncthreads();

  float* outb = out + (size_t)b * OUT_PER_B;
  int base = p * 48 + q * 3;
  for (int t = tid; t < NK * 3; t += 256) {
    int k = t / 3, c = t - 3 * k;
    int f = k * 768 + base + c;           // flat [K,P,P,C] index
    outb[(f & 255) * 300 + (f >> 8)] = sk[t];  // view(B,300,256) + transpose
  }
}

extern "C" void kernel_launch(void* const* d_in, const int* in_sizes, int n_in,
                              void* d_out, int out_size, void* d_ws, size_t ws_size,
                              hipStream_t stream) {
  const float* x = (const float*)d_in[0];
  float* out = (float*)d_out;
  char* ws = (char*)d_ws;
  // ws layout:
  float* A        = (float*)(ws);              // 14336 B
  float* centers  = (float*)(ws + 16384);      // 16000 B
  float* c2g      = (float*)(ws + 49152);      // 3200 B
  int*   labels   = (int*)(ws + 90112);        // 1605632 B
  float* partials = (float*)(ws + 1703936);    // 8*100*6*131*4 = 2515200 B

  build_A_kernel<<<16, 256, 0, stream>>>(A);
  init_centers_kernel<<<NB, 128, 0, stream>>>(x, centers, c2g);

  dim3 cgrid(NCHUNK, NB);         // 131 x 8
  for (int it = 0; it < 10; ++it) {
    fused_assign_partial_kernel<<<cgrid, 256, 0, stream>>>(x, centers, c2g, partials);
    combine_update_kernel<<<NB, 128, 0, stream>>>(centers, partials, c2g);
  }
  dim3 agrid(49, NB);             // 49*1024 = 50176 exact
  assign_kernel<<<agrid, 256, 0, stream>>>(x, centers, c2g, labels);

  dim3 egrid(256, NB);            // (p*16+q) x b
  embed_kernel<<<egrid, 256, 0, stream>>>(x, labels, A, out);
}

// Round 10
// 625.544 us; speedup vs baseline: 1.0010x; 1.0010x over previous
//
#include <hip/hip_runtime.h>
#include <math.h>

#define IMGD 224
#define HW 50176      // 224*224
#define NK 100
#define NB 8
#define OUT_PER_B 76800   // 100*16*16*3 = 300*256
#define NCHUNK 131        // OpenBLAS k-blocking of 50176: 129x384, 320, 320

// ratio = 10.0 / sqrt(224*224/100) in f64, rounded to f32 when numpy multiplies
// the f32 arange arrays by the weak python scalar.
static __device__ __forceinline__ float ratio_f32() {
  return (float)(10.0 / sqrt(224.0 * 224.0 / 100.0));
}

// ---------- resize matrix A[16][224], jax linear+antialias semantics ----------
__global__ void build_A_kernel(float* __restrict__ A) {
  __shared__ float red[256];
  int p = blockIdx.x;   // 0..15
  int h = threadIdx.x;  // 0..255
  float tri = 0.0f;
  if (h < IMGD) {
    float center = (p + 0.5f) * 14.0f - 0.5f;       // sample_f
    float xd = fabsf(center - (float)h) / 14.0f;    // / kernel_scale
    tri = fmaxf(0.0f, 1.0f - xd);
  }
  red[h] = tri;
  __syncthreads();
  for (int s = 128; s > 0; s >>= 1) {
    if (h < s) red[h] += red[h + s];
    __syncthreads();
  }
  float Z = red[0];
  if (h < IMGD) A[p * IMGD + h] = tri / Z;
}

// ---------- SLIC: grid-init centers (f32, mirroring numpy) + c2 ----------
__global__ void init_centers_kernel(const float* __restrict__ x,
                                    float* __restrict__ centers,
                                    float* __restrict__ c2g) {
  int b = blockIdx.x, k = threadIdx.x;
  if (k >= NK) return;
  int gy = k / 10, gx = k % 10;
  int cy = (int)((gy + 0.5) * 224.0 / 10.0);  // trunc like .astype(int32)
  int cx = (int)((gx + 0.5) * 224.0 / 10.0);
  int i = cy * IMGD + cx;
  const float ratio = ratio_f32();
  float c0 = x[((size_t)b * 3 + 0) * HW + i];
  float c1 = x[((size_t)b * 3 + 1) * HW + i];
  float c2 = x[((size_t)b * 3 + 2) * HW + i];
  float c3 = __fmul_rn((float)cy, ratio);
  float c4 = __fmul_rn((float)cx, ratio);
  float* c = centers + ((size_t)b * NK + k) * 5;
  c[0] = c0; c[1] = c1; c[2] = c2; c[3] = c3; c[4] = c4;
  // c2 = np.sum(centers*centers, axis=1): rounded products, sequential adds
  float s = __fmul_rn(c0, c0);
  s = __fadd_rn(s, __fmul_rn(c1, c1));
  s = __fadd_rn(s, __fmul_rn(c2, c2));
  s = __fadd_rn(s, __fmul_rn(c3, c3));
  s = __fadd_rn(s, __fmul_rn(c4, c4));
  c2g[(size_t)b * NK + k] = s;
}

// distance op sequence — the single source of truth for bit-exactness:
// dot = fmul(f0,c0); fma(f1,c1); fma(f2,c2); fma(f3,c3); fma(f4,c4)
// d   = fsub(fadd(fsq, c2k), fmul(2, dot))
static __device__ __forceinline__ float dist5(float f0, float f1, float f2,
                                              float f3, float f4, float fsq,
                                              float4 c4v, float2 c2v) {
  float dot = __fmul_rn(f0, c4v.x);
  dot = __fmaf_rn(f1, c4v.y, dot);
  dot = __fmaf_rn(f2, c4v.z, dot);
  dot = __fmaf_rn(f3, c4v.w, dot);
  dot = __fmaf_rn(f4, c2v.x, dot);
  return __fsub_rn(__fadd_rn(fsq, c2v.y), __fmul_rn(2.0f, dot));
}

// fsq = np.sum(feat*feat): rounded products, sequential adds, no FMA
static __device__ __forceinline__ float fsq5(float f0, float f1, float f2,
                                             float f3, float f4) {
  float s = __fmul_rn(f0, f0);
  s = __fadd_rn(s, __fmul_rn(f1, f1));
  s = __fadd_rn(s, __fmul_rn(f2, f2));
  s = __fadd_rn(s, __fmul_rn(f3, f3));
  s = __fadd_rn(s, __fmul_rn(f4, f4));
  return s;
}

// ---------- full-image assignment: 4 px/thread, packed LDS centers ----------
// Empirically ~6 us = near the 5.3 us VALU floor; used EVERY iteration.
__global__ void __launch_bounds__(256) assign_kernel(
    const float* __restrict__ x, const float* __restrict__ centers,
    const float* __restrict__ c2g, int* __restrict__ labels) {
  __shared__ float4 ck4[NK];
  __shared__ float2 ck2[NK];
  int b = blockIdx.y;
  int tid = threadIdx.x;
  int base = blockIdx.x * 1024;   // grid.x = 49 -> 49*1024 = 50176 exact

  const float* cb = centers + (size_t)b * NK * 5;
  const float* c2b = c2g + (size_t)b * NK;
  for (int k = tid; k < NK; k += 256) {
    ck4[k] = make_float4(cb[k * 5 + 0], cb[k * 5 + 1], cb[k * 5 + 2], cb[k * 5 + 3]);
    ck2[k] = make_float2(cb[k * 5 + 4], c2b[k]);
  }
  __syncthreads();

  const float* x0 = x + (size_t)b * 3 * HW;
  const float ratio = ratio_f32();
  float f0[4], f1[4], f2[4], f3[4], f4[4], fq[4];
  float best[4]; int bk[4];
  for (int r = 0; r < 4; ++r) {
    int i = base + r * 256 + tid;   // coalesced
    int y = i / IMGD, xw = i - y * IMGD;
    f0[r] = x0[i]; f1[r] = x0[HW + i]; f2[r] = x0[2 * HW + i];
    f3[r] = __fmul_rn((float)y, ratio);
    f4[r] = __fmul_rn((float)xw, ratio);
    fq[r] = fsq5(f0[r], f1[r], f2[r], f3[r], f4[r]);
    best[r] = 3.4e38f; bk[r] = 0;
  }
  for (int k = 0; k < NK; ++k) {
    float4 c4v = ck4[k];
    float2 c2v = ck2[k];
    for (int r = 0; r < 4; ++r) {
      float d = dist5(f0[r], f1[r], f2[r], f3[r], f4[r], fq[r], c4v, c2v);
      if (d < best[r]) { best[r] = d; bk[r] = k; }  // first-index wins (np.argmin)
    }
  }
  int* lb = labels + (size_t)b * HW;
  for (int r = 0; r < 4; ++r) lb[base + r * 256 + tid] = bk[r];
}

// ---------- partial: compaction-only (reads labels), one OpenBLAS chunk ----------
// Stable counting-sort VALUE compaction; the per-(k,chunk) f32 add chain walks
// consecutive LDS addresses in ascending-pixel order -> bit-identical to the
// sequential blocked-sgemm reference.
__global__ void __launch_bounds__(256) partial_kernel(
    const float* __restrict__ x, const int* __restrict__ labels,
    float* __restrict__ partials_t) {
  __shared__ unsigned int mask[NK * 12];    // 12 groups of 32 pixels
  __shared__ unsigned short ppk[NK * 12];   // per-(k,g) exclusive popcount prefix
  __shared__ float4 cval4[384];             // compacted {r,g,b,f3}, ascending t per k
  __shared__ float  cvalf[384];             // compacted f4
  __shared__ int cnt[128];
  __shared__ int offx[128];                 // inclusive prefix of cnt
  __shared__ int wtot;
  int c = blockIdx.x, b = blockIdx.y;
  int tid = threadIdx.x;
  int start = (c < 129) ? c * 384 : 49536 + (c - 129) * 320;
  int len   = (c < 129) ? 384 : 320;

  for (int t = tid; t < NK * 12; t += 256) mask[t] = 0u;
  __syncthreads();

  const float* x0 = x + (size_t)b * 3 * HW;
  const int* lb = labels + (size_t)b * HW;
  const float ratio = ratio_f32();

  int t1 = 256 + tid;
  bool v1 = t1 < len;               // t0=tid always valid (256 <= len)

  int i0 = start + tid;
  int y0 = i0 / IMGD, w0 = i0 - y0 * IMGD;
  float a0 = x0[i0], a1 = x0[HW + i0], a2 = x0[2 * HW + i0];
  float a3 = __fmul_rn((float)y0, ratio), a4 = __fmul_rn((float)w0, ratio);
  int bkA = lb[i0];

  int i1 = start + (v1 ? t1 : 0);
  int y1 = i1 / IMGD, w1 = i1 - y1 * IMGD;
  float e0 = x0[i1], e1 = x0[HW + i1], e2 = x0[2 * HW + i1];
  float e3 = __fmul_rn((float)y1, ratio), e4 = __fmul_rn((float)w1, ratio);
  int bkE = v1 ? lb[i1] : 0;

  atomicOr(&mask[bkA * 12 + (tid >> 5)], 1u << (tid & 31));
  if (v1) atomicOr(&mask[bkE * 12 + (t1 >> 5)], 1u << (t1 & 31));
  __syncthreads();

  // per-k cumulative popcounts over the 12 groups
  int myCnt = 0;
  if (tid < NK) {
    int s = 0;
    for (int g = 0; g < 12; ++g) {
      ppk[tid * 12 + g] = (unsigned short)s;
      s += __popc(mask[tid * 12 + g]);
    }
    myCnt = s;
  }
  if (tid < 128) cnt[tid] = myCnt;
  __syncthreads();

  // inclusive prefix over 128 counts: shfl scan per wave + cross-wave fixup
  int v = (tid < 128) ? cnt[tid] : 0;
  if (tid < 128) {
    for (int d = 1; d < 64; d <<= 1) {
      int u = __shfl_up(v, d, 64);
      if ((tid & 63) >= d) v += u;
    }
  }
  if (tid == 63) wtot = v;
  __syncthreads();
  if (tid >= 64 && tid < 128) v += wtot;
  if (tid < 128) offx[tid] = v;
  __syncthreads();

  // stable VALUE scatter: pos = (off[k]-cnt[k]) + rank_within_k(t)
  {
    int g = tid >> 5, j = tid & 31;
    int rank = ppk[bkA * 12 + g] + __popc(mask[bkA * 12 + g] & ((1u << j) - 1u));
    int pos = offx[bkA] - cnt[bkA] + rank;
    cval4[pos] = make_float4(a0, a1, a2, a3);
    cvalf[pos] = a4;
  }
  if (v1) {
    int g = t1 >> 5, j = t1 & 31;
    int rank = ppk[bkE * 12 + g] + __popc(mask[bkE * 12 + g] & ((1u << j) - 1u));
    int pos = offx[bkE] - cnt[bkE] + rank;
    cval4[pos] = make_float4(e0, e1, e2, e3);
    cvalf[pos] = e4;
  }
  __syncthreads();

  // scan: thread k walks its consecutive compacted range (ascending t)
  if (tid < NK) {
    int n = cnt[tid];
    int base = offx[tid] - n;
    float s0 = 0.f, s1 = 0.f, s2 = 0.f, s3 = 0.f, s4 = 0.f, s5 = 0.f;
    for (int m = 0; m < n; ++m) {
      float4 vv = cval4[base + m];   // consecutive addresses: pipelineable
      float ww = cvalf[base + m];
      s0 = __fadd_rn(s0, vv.x);
      s1 = __fadd_rn(s1, vv.y);
      s2 = __fadd_rn(s2, vv.z);
      s3 = __fadd_rn(s3, vv.w);
      s4 = __fadd_rn(s4, ww);
      s5 += 1.0f;  // counts: exact
    }
    // transposed layout [b][k][j][c] so combine reads contiguous
    float* p = partials_t + (((size_t)b * NK + tid) * 6) * NCHUNK + c;
    p[0 * NCHUNK] = s0; p[1 * NCHUNK] = s1; p[2 * NCHUNK] = s2;
    p[3 * NCHUNK] = s3; p[4 * NCHUNK] = s4; p[5 * NCHUNK] = s5;
  }
}

// ---------- combine k-blocks in order + centroid update + c2 (all f32) ----------
// 6 independent 131-step chains per (b,k), contiguous addresses each.
__global__ void combine_update_kernel(float* __restrict__ centers,
                                      const float* __restrict__ partials_t,
                                      float* __restrict__ c2g) {
  int b = blockIdx.x, k = threadIdx.x;
  if (k >= NK) return;
  const float* base = partials_t + (((size_t)b * NK + k) * 6) * NCHUNK;
  float s0 = base[0 * NCHUNK], s1 = base[1 * NCHUNK], s2 = base[2 * NCHUNK];
  float s3 = base[3 * NCHUNK], s4 = base[4 * NCHUNK], s5 = base[5 * NCHUNK];
  for (int c = 1; c < NCHUNK; ++c) {   // ascending chunk order: C += block_c
    s0 = __fadd_rn(s0, base[0 * NCHUNK + c]);
    s1 = __fadd_rn(s1, base[1 * NCHUNK + c]);
    s2 = __fadd_rn(s2, base[2 * NCHUNK + c]);
    s3 = __fadd_rn(s3, base[3 * NCHUNK + c]);
    s4 = __fadd_rn(s4, base[4 * NCHUNK + c]);
    s5 = __fadd_rn(s5, base[5 * NCHUNK + c]);
  }
  float* cc = centers + ((size_t)b * NK + k) * 5;
  if (s5 > 0.0f) {                  // where(cnt>0, new, centers)
    float m = fmaxf(s5, 1.0f);      // np.maximum(cnt, 1.0): exact int in f32
    cc[0] = __fdiv_rn(s0, m);
    cc[1] = __fdiv_rn(s1, m);
    cc[2] = __fdiv_rn(s2, m);
    cc[3] = __fdiv_rn(s3, m);
    cc[4] = __fdiv_rn(s4, m);
  }
  // recompute c2 from the (possibly unchanged) stored center, same op order
  float c0 = cc[0], c1 = cc[1], c2 = cc[2], c3 = cc[3], c4 = cc[4];
  float t = __fmul_rn(c0, c0);
  t = __fadd_rn(t, __fmul_rn(c1, c1));
  t = __fadd_rn(t, __fmul_rn(c2, c2));
  t = __fadd_rn(t, __fmul_rn(c3, c3));
  t = __fadd_rn(t, __fmul_rn(c4, c4));
  c2g[(size_t)b * NK + k] = t;
}

// ---------- embed: block = (b,p,q); LDS bins per (k,c); direct stores ----------
__global__ void __launch_bounds__(256) embed_kernel(
    const float* __restrict__ x, const int* __restrict__ labels,
    const float* __restrict__ A, float* __restrict__ out) {
  __shared__ float sk[NK * 3];
  int b = blockIdx.y;
  int p = blockIdx.x >> 4;
  int q = blockIdx.x & 15;
  int tid = threadIdx.x;
  for (int t = tid; t < NK * 3; t += 256) sk[t] = 0.0f;
  __syncthreads();

  // A[p,h] support: h in [14p-7, 14p+20] clipped
  int h0 = max(0, 14 * p - 7), h1 = min(IMGD - 1, 14 * p + 20);
  int w0 = max(0, 14 * q - 7), w1 = min(IMGD - 1, 14 * q + 20);
  int hl = h1 - h0 + 1, wl = w1 - w0 + 1;
  int n = hl * wl;

  const float* xb = x + (size_t)b * 3 * HW;
  const int* lb = labels + (size_t)b * HW;
  const float* Ap = A + p * IMGD;
  const float* Aq = A + q * IMGD;

  for (int idx = tid; idx < n; idx += 256) {
    int dh = idx / wl;
    int hh = h0 + dh;
    int ww = w0 + (idx - dh * wl);
    int i = hh * IMGD + ww;
    float wgt = Ap[hh] * Aq[ww];
    int k = lb[i];
    atomicAdd(&sk[k * 3 + 0], wgt * xb[i]);
    atomicAdd(&sk[k * 3 + 1], wgt * xb[HW + i]);
    atomicAdd(&sk[k * 3 + 2], wgt * xb[2 * HW + i]);
  }
  __syncthreads();

  float* outb = out + (size_t)b * OUT_PER_B;
  int base = p * 48 + q * 3;
  for (int t = tid; t < NK * 3; t += 256) {
    int k = t / 3, c = t - 3 * k;
    int f = k * 768 + base + c;           // flat [K,P,P,C] index
    outb[(f & 255) * 300 + (f >> 8)] = sk[t];  // view(B,300,256) + transpose
  }
}

extern "C" void kernel_launch(void* const* d_in, const int* in_sizes, int n_in,
                              void* d_out, int out_size, void* d_ws, size_t ws_size,
                              hipStream_t stream) {
  const float* x = (const float*)d_in[0];
  float* out = (float*)d_out;
  char* ws = (char*)d_ws;
  // ws layout:
  float* A        = (float*)(ws);              // 14336 B
  float* centers  = (float*)(ws + 16384);      // 16000 B
  float* c2g      = (float*)(ws + 49152);      // 3200 B
  int*   labels   = (int*)(ws + 90112);        // 1605632 B
  float* partials = (float*)(ws + 1703936);    // 8*100*6*131*4 = 2515200 B

  build_A_kernel<<<16, 256, 0, stream>>>(A);
  init_centers_kernel<<<NB, 128, 0, stream>>>(x, centers, c2g);

  dim3 agrid(49, NB);             // 49*1024 = 50176 exact
  dim3 cgrid(NCHUNK, NB);         // 131 x 8
  for (int it = 0; it < 10; ++it) {
    assign_kernel<<<agrid, 256, 0, stream>>>(x, centers, c2g, labels);
    partial_kernel<<<cgrid, 256, 0, stream>>>(x, labels, partials);
    combine_update_kernel<<<NB, 128, 0, stream>>>(centers, partials, c2g);
  }
  assign_kernel<<<agrid, 256, 0, stream>>>(x, centers, c2g, labels);

  dim3 egrid(256, NB);            // (p*16+q) x b
  embed_kernel<<<egrid, 256, 0, stream>>>(x, labels, A, out);
}

// Round 11
// 377.370 us; speedup vs baseline: 1.6593x; 1.6576x over previous
//
#include <hip/hip_runtime.h>
#include <math.h>

#define IMGD 224
#define HW 50176      // 224*224
#define NK 100
#define NB 8
#define OUT_PER_B 76800   // 100*16*16*3 = 300*256
#define NCHUNK 131        // OpenBLAS k-blocking of 50176: 129x384, 320, 320

// ratio = 10.0 / sqrt(224*224/100) in f64, rounded to f32 when numpy multiplies
// the f32 arange arrays by the weak python scalar.
static __device__ __forceinline__ float ratio_f32() {
  return (float)(10.0 / sqrt(224.0 * 224.0 / 100.0));
}

// ---------- resize matrix A[16][224], jax linear+antialias semantics ----------
__global__ void build_A_kernel(float* __restrict__ A) {
  __shared__ float red[256];
  int p = blockIdx.x;   // 0..15
  int h = threadIdx.x;  // 0..255
  float tri = 0.0f;
  if (h < IMGD) {
    float center = (p + 0.5f) * 14.0f - 0.5f;       // sample_f
    float xd = fabsf(center - (float)h) / 14.0f;    // / kernel_scale
    tri = fmaxf(0.0f, 1.0f - xd);
  }
  red[h] = tri;
  __syncthreads();
  for (int s = 128; s > 0; s >>= 1) {
    if (h < s) red[h] += red[h + s];
    __syncthreads();
  }
  float Z = red[0];
  if (h < IMGD) A[p * IMGD + h] = tri / Z;
}

// ---------- SLIC: grid-init centers (f32, mirroring numpy) + c2 ----------
__global__ void init_centers_kernel(const float* __restrict__ x,
                                    float* __restrict__ centers,
                                    float* __restrict__ c2g) {
  int b = blockIdx.x, k = threadIdx.x;
  if (k >= NK) return;
  int gy = k / 10, gx = k % 10;
  int cy = (int)((gy + 0.5) * 224.0 / 10.0);  // trunc like .astype(int32)
  int cx = (int)((gx + 0.5) * 224.0 / 10.0);
  int i = cy * IMGD + cx;
  const float ratio = ratio_f32();
  float c0 = x[((size_t)b * 3 + 0) * HW + i];
  float c1 = x[((size_t)b * 3 + 1) * HW + i];
  float c2 = x[((size_t)b * 3 + 2) * HW + i];
  float c3 = __fmul_rn((float)cy, ratio);
  float c4 = __fmul_rn((float)cx, ratio);
  float* c = centers + ((size_t)b * NK + k) * 5;
  c[0] = c0; c[1] = c1; c[2] = c2; c[3] = c3; c[4] = c4;
  // c2 = np.sum(centers*centers, axis=1): rounded products, sequential adds
  float s = __fmul_rn(c0, c0);
  s = __fadd_rn(s, __fmul_rn(c1, c1));
  s = __fadd_rn(s, __fmul_rn(c2, c2));
  s = __fadd_rn(s, __fmul_rn(c3, c3));
  s = __fadd_rn(s, __fmul_rn(c4, c4));
  c2g[(size_t)b * NK + k] = s;
}

// distance op sequence — the single source of truth for bit-exactness:
// dot = fmul(f0,c0); fma(f1,c1); fma(f2,c2); fma(f3,c3); fma(f4,c4)
// d   = fsub(fadd(fsq, c2k), fmul(2, dot))
static __device__ __forceinline__ float dist5(float f0, float f1, float f2,
                                              float f3, float f4, float fsq,
                                              float4 c4v, float2 c2v) {
  float dot = __fmul_rn(f0, c4v.x);
  dot = __fmaf_rn(f1, c4v.y, dot);
  dot = __fmaf_rn(f2, c4v.z, dot);
  dot = __fmaf_rn(f3, c4v.w, dot);
  dot = __fmaf_rn(f4, c2v.x, dot);
  return __fsub_rn(__fadd_rn(fsq, c2v.y), __fmul_rn(2.0f, dot));
}

// fsq = np.sum(feat*feat): rounded products, sequential adds, no FMA
static __device__ __forceinline__ float fsq5(float f0, float f1, float f2,
                                             float f3, float f4) {
  float s = __fmul_rn(f0, f0);
  s = __fadd_rn(s, __fmul_rn(f1, f1));
  s = __fadd_rn(s, __fmul_rn(f2, f2));
  s = __fadd_rn(s, __fmul_rn(f3, f3));
  s = __fadd_rn(s, __fmul_rn(f4, f4));
  return s;
}

// ---------- full-image assignment: 2 px/thread, k-batched by 4 ----------
// grid 98x8 = 784 blocks (~12 waves/CU for latency hiding); 8 LDS center
// loads issued per k-batch -> 25 wait regions instead of 100. Per-px op
// order (ascending k, strict <) identical to the numpy mirror.
__global__ void __launch_bounds__(256) assign_kernel(
    const float* __restrict__ x, const float* __restrict__ centers,
    const float* __restrict__ c2g, int* __restrict__ labels) {
  __shared__ float4 ck4[NK];
  __shared__ float2 ck2[NK];
  int b = blockIdx.y;
  int tid = threadIdx.x;
  int base = blockIdx.x * 512;   // grid.x = 98 -> 98*512 = 50176 exact

  const float* cb = centers + (size_t)b * NK * 5;
  const float* c2b = c2g + (size_t)b * NK;
  for (int k = tid; k < NK; k += 256) {
    ck4[k] = make_float4(cb[k * 5 + 0], cb[k * 5 + 1], cb[k * 5 + 2], cb[k * 5 + 3]);
    ck2[k] = make_float2(cb[k * 5 + 4], c2b[k]);
  }
  __syncthreads();

  const float* x0 = x + (size_t)b * 3 * HW;
  const float ratio = ratio_f32();
  float f0[2], f1[2], f2[2], f3[2], f4[2], fq[2];
  float best[2]; int bk[2];
  for (int r = 0; r < 2; ++r) {
    int i = base + r * 256 + tid;   // coalesced
    int y = i / IMGD, xw = i - y * IMGD;
    f0[r] = x0[i]; f1[r] = x0[HW + i]; f2[r] = x0[2 * HW + i];
    f3[r] = __fmul_rn((float)y, ratio);
    f4[r] = __fmul_rn((float)xw, ratio);
    fq[r] = fsq5(f0[r], f1[r], f2[r], f3[r], f4[r]);
    best[r] = 3.4e38f; bk[r] = 0;
  }
  for (int kb = 0; kb < NK; kb += 4) {   // NK=100 -> 25 batches
    float4 a4[4]; float2 a2[4];
    for (int kk = 0; kk < 4; ++kk) { a4[kk] = ck4[kb + kk]; a2[kk] = ck2[kb + kk]; }
    for (int kk = 0; kk < 4; ++kk) {
      for (int r = 0; r < 2; ++r) {
        float d = dist5(f0[r], f1[r], f2[r], f3[r], f4[r], fq[r], a4[kk], a2[kk]);
        if (d < best[r]) { best[r] = d; bk[r] = kb + kk; }  // first-index wins
      }
    }
  }
  int* lb = labels + (size_t)b * HW;
  for (int r = 0; r < 2; ++r) lb[base + r * 256 + tid] = bk[r];
}

// ---------- partial: compaction-only (reads labels), one OpenBLAS chunk ----------
// Stable counting-sort VALUE compaction; the per-(k,chunk) f32 add chain walks
// consecutive LDS addresses in ascending-pixel order -> bit-identical to the
// sequential blocked-sgemm reference.
__global__ void __launch_bounds__(256) partial_kernel(
    const float* __restrict__ x, const int* __restrict__ labels,
    float* __restrict__ partials_t) {
  __shared__ unsigned int mask[NK * 12];    // 12 groups of 32 pixels
  __shared__ unsigned short ppk[NK * 12];   // per-(k,g) exclusive popcount prefix
  __shared__ float4 cval4[384];             // compacted {r,g,b,f3}, ascending t per k
  __shared__ float  cvalf[384];             // compacted f4
  __shared__ int cnt[128];
  __shared__ int offx[128];                 // inclusive prefix of cnt
  __shared__ int wtot;
  int c = blockIdx.x, b = blockIdx.y;
  int tid = threadIdx.x;
  int start = (c < 129) ? c * 384 : 49536 + (c - 129) * 320;
  int len   = (c < 129) ? 384 : 320;

  for (int t = tid; t < NK * 12; t += 256) mask[t] = 0u;
  __syncthreads();

  const float* x0 = x + (size_t)b * 3 * HW;
  const int* lb = labels + (size_t)b * HW;
  const float ratio = ratio_f32();

  int t1 = 256 + tid;
  bool v1 = t1 < len;               // t0=tid always valid (256 <= len)

  int i0 = start + tid;
  int y0 = i0 / IMGD, w0 = i0 - y0 * IMGD;
  float a0 = x0[i0], a1 = x0[HW + i0], a2 = x0[2 * HW + i0];
  float a3 = __fmul_rn((float)y0, ratio), a4 = __fmul_rn((float)w0, ratio);
  int bkA = lb[i0];

  int i1 = start + (v1 ? t1 : 0);
  int y1 = i1 / IMGD, w1 = i1 - y1 * IMGD;
  float e0 = x0[i1], e1 = x0[HW + i1], e2 = x0[2 * HW + i1];
  float e3 = __fmul_rn((float)y1, ratio), e4 = __fmul_rn((float)w1, ratio);
  int bkE = v1 ? lb[i1] : 0;

  atomicOr(&mask[bkA * 12 + (tid >> 5)], 1u << (tid & 31));
  if (v1) atomicOr(&mask[bkE * 12 + (t1 >> 5)], 1u << (t1 & 31));
  __syncthreads();

  // per-k cumulative popcounts over the 12 groups
  int myCnt = 0;
  if (tid < NK) {
    int s = 0;
    for (int g = 0; g < 12; ++g) {
      ppk[tid * 12 + g] = (unsigned short)s;
      s += __popc(mask[tid * 12 + g]);
    }
    myCnt = s;
  }
  if (tid < 128) cnt[tid] = myCnt;
  __syncthreads();

  // inclusive prefix over 128 counts: shfl scan per wave + cross-wave fixup
  int v = (tid < 128) ? cnt[tid] : 0;
  if (tid < 128) {
    for (int d = 1; d < 64; d <<= 1) {
      int u = __shfl_up(v, d, 64);
      if ((tid & 63) >= d) v += u;
    }
  }
  if (tid == 63) wtot = v;
  __syncthreads();
  if (tid >= 64 && tid < 128) v += wtot;
  if (tid < 128) offx[tid] = v;
  __syncthreads();

  // stable VALUE scatter: pos = (off[k]-cnt[k]) + rank_within_k(t)
  {
    int g = tid >> 5, j = tid & 31;
    int rank = ppk[bkA * 12 + g] + __popc(mask[bkA * 12 + g] & ((1u << j) - 1u));
    int pos = offx[bkA] - cnt[bkA] + rank;
    cval4[pos] = make_float4(a0, a1, a2, a3);
    cvalf[pos] = a4;
  }
  if (v1) {
    int g = t1 >> 5, j = t1 & 31;
    int rank = ppk[bkE * 12 + g] + __popc(mask[bkE * 12 + g] & ((1u << j) - 1u));
    int pos = offx[bkE] - cnt[bkE] + rank;
    cval4[pos] = make_float4(e0, e1, e2, e3);
    cvalf[pos] = e4;
  }
  __syncthreads();

  // scan: thread k walks its consecutive compacted range (ascending t)
  if (tid < NK) {
    int n = cnt[tid];
    int base = offx[tid] - n;
    float s0 = 0.f, s1 = 0.f, s2 = 0.f, s3 = 0.f, s4 = 0.f, s5 = 0.f;
    for (int m = 0; m < n; ++m) {
      float4 vv = cval4[base + m];   // consecutive addresses: pipelineable
      float ww = cvalf[base + m];
      s0 = __fadd_rn(s0, vv.x);
      s1 = __fadd_rn(s1, vv.y);
      s2 = __fadd_rn(s2, vv.z);
      s3 = __fadd_rn(s3, vv.w);
      s4 = __fadd_rn(s4, ww);
      s5 += 1.0f;  // counts: exact
    }
    // transposed layout [b][k][j][c] so combine reads contiguous
    float* p = partials_t + (((size_t)b * NK + tid) * 6) * NCHUNK + c;
    p[0 * NCHUNK] = s0; p[1 * NCHUNK] = s1; p[2 * NCHUNK] = s2;
    p[3 * NCHUNK] = s3; p[4 * NCHUNK] = s4; p[5 * NCHUNK] = s5;
  }
}

// ---------- combine: one block per (b,k); LDS-staged 131-chains ----------
// 128 threads stage the 786 contiguous partials (parallel, coalesced); then
// 6 threads run the sequential ascending-chunk chains LDS-fed (banks j*131%32
// never collide). Same add order as the blocked-sgemm reference.
__global__ void __launch_bounds__(128) combine_update_kernel(
    float* __restrict__ centers, const float* __restrict__ partials_t,
    float* __restrict__ c2g) {
  __shared__ float st[6 * NCHUNK];
  __shared__ float sums[6];
  __shared__ float newc[5];
  int bk = blockIdx.x;                 // b*NK + k
  int tid = threadIdx.x;
  const float* base = partials_t + (size_t)bk * 6 * NCHUNK;
  for (int t = tid; t < 6 * NCHUNK; t += 128) st[t] = base[t];
  __syncthreads();
  if (tid < 6) {
    const float* row = st + tid * NCHUNK;
    float s = row[0];                  // C = 0 + chunk0 (exact)
    for (int c = 1; c < NCHUNK; ++c) s = __fadd_rn(s, row[c]);
    sums[tid] = s;
  }
  __syncthreads();
  float cntv = sums[5];
  float* cc = centers + (size_t)bk * 5;
  if (tid < 5) {
    float v;
    if (cntv > 0.0f) {                 // where(cnt>0, new, centers)
      float m = fmaxf(cntv, 1.0f);     // np.maximum(cnt,1.0): exact int in f32
      v = __fdiv_rn(sums[tid], m);
      cc[tid] = v;
    } else {
      v = cc[tid];                     // unchanged center
    }
    newc[tid] = v;
  }
  __syncthreads();
  if (tid == 0) {
    // c2 = sum(centers*centers): rounded products, sequential adds
    float t0 = __fmul_rn(newc[0], newc[0]);
    t0 = __fadd_rn(t0, __fmul_rn(newc[1], newc[1]));
    t0 = __fadd_rn(t0, __fmul_rn(newc[2], newc[2]));
    t0 = __fadd_rn(t0, __fmul_rn(newc[3], newc[3]));
    t0 = __fadd_rn(t0, __fmul_rn(newc[4], newc[4]));
    c2g[bk] = t0;
  }
}

// ---------- embed: block = (b,p,q); LDS bins per (k,c); direct stores ----------
__global__ void __launch_bounds__(256) embed_kernel(
    const float* __restrict__ x, const int* __restrict__ labels,
    const float* __restrict__ A, float* __restrict__ out) {
  __shared__ float sk[NK * 3];
  int b = blockIdx.y;
  int p = blockIdx.x >> 4;
  int q = blockIdx.x & 15;
  int tid = threadIdx.x;
  for (int t = tid; t < NK * 3; t += 256) sk[t] = 0.0f;
  __syncthreads();

  // A[p,h] support: h in [14p-7, 14p+20] clipped
  int h0 = max(0, 14 * p - 7), h1 = min(IMGD - 1, 14 * p + 20);
  int w0 = max(0, 14 * q - 7), w1 = min(IMGD - 1, 14 * q + 20);
  int hl = h1 - h0 + 1, wl = w1 - w0 + 1;
  int n = hl * wl;

  const float* xb = x + (size_t)b * 3 * HW;
  const int* lb = labels + (size_t)b * HW;
  const float* Ap = A + p * IMGD;
  const float* Aq = A + q * IMGD;

  for (int idx = tid; idx < n; idx += 256) {
    int dh = idx / wl;
    int hh = h0 + dh;
    int ww = w0 + (idx - dh * wl);
    int i = hh * IMGD + ww;
    float wgt = Ap[hh] * Aq[ww];
    int k = lb[i];
    atomicAdd(&sk[k * 3 + 0], wgt * xb[i]);
    atomicAdd(&sk[k * 3 + 1], wgt * xb[HW + i]);
    atomicAdd(&sk[k * 3 + 2], wgt * xb[2 * HW + i]);
  }
  __syncthreads();

  float* outb = out + (size_t)b * OUT_PER_B;
  int base = p * 48 + q * 3;
  for (int t = tid; t < NK * 3; t += 256) {
    int k = t / 3, c = t - 3 * k;
    int f = k * 768 + base + c;           // flat [K,P,P,C] index
    outb[(f & 255) * 300 + (f >> 8)] = sk[t];  // view(B,300,256) + transpose
  }
}

extern "C" void kernel_launch(void* const* d_in, const int* in_sizes, int n_in,
                              void* d_out, int out_size, void* d_ws, size_t ws_size,
                              hipStream_t stream) {
  const float* x = (const float*)d_in[0];
  float* out = (float*)d_out;
  char* ws = (char*)d_ws;
  // ws layout:
  float* A        = (float*)(ws);              // 14336 B
  float* centers  = (float*)(ws + 16384);      // 16000 B
  float* c2g      = (float*)(ws + 49152);      // 3200 B
  int*   labels   = (int*)(ws + 90112);        // 1605632 B
  float* partials = (float*)(ws + 1703936);    // 8*100*6*131*4 = 2515200 B

  build_A_kernel<<<16, 256, 0, stream>>>(A);
  init_centers_kernel<<<NB, 128, 0, stream>>>(x, centers, c2g);

  dim3 agrid(98, NB);             // 98*512 = 50176 exact
  dim3 cgrid(NCHUNK, NB);         // 131 x 8
  for (int it = 0; it < 10; ++it) {
    assign_kernel<<<agrid, 256, 0, stream>>>(x, centers, c2g, labels);
    partial_kernel<<<cgrid, 256, 0, stream>>>(x, labels, partials);
    combine_update_kernel<<<NB * NK, 128, 0, stream>>>(centers, partials, c2g);
  }
  assign_kernel<<<agrid, 256, 0, stream>>>(x, centers, c2g, labels);

  dim3 egrid(256, NB);            // (p*16+q) x b
  embed_kernel<<<egrid, 256, 0, stream>>>(x, labels, A, out);
}